// Round 4
// baseline (7869.376 us; speedup 1.0000x reference)
//
#include <hip/hip_runtime.h>
#include <hip/hip_cooperative_groups.h>
#include <math.h>

namespace cg = cooperative_groups;

#define NQ2 2048      // nx = nq = 2048
#define NT  4096      // nx + nq
#define NUU 16
#define FEPS 0.01f
#define NB  64
#define NBLK 32       // 2048 / 64
#define GCH 16        // split-K chunks for transposed GEMVs

typedef __attribute__((ext_vector_type(8))) short short8;
typedef __attribute__((ext_vector_type(4))) float floatx4;

__device__ __forceinline__ float readlane_f(float v, int lane) {
  return __int_as_float(__builtin_amdgcn_readlane(__float_as_int(v), lane));
}

__device__ __forceinline__ unsigned short f2bf(float x) {
  unsigned u = __float_as_uint(x);
  unsigned r = u + 0x7FFFu + ((u >> 16) & 1u);
  return (unsigned short)(r >> 16);
}
__device__ __forceinline__ float bf2f(unsigned short h) {
  return __uint_as_float(((unsigned)h) << 16);
}

// ---------------- reductions ----------------
__device__ __forceinline__ float wave_reduce(float v) {
#pragma unroll
  for (int off = 32; off > 0; off >>= 1) v += __shfl_down(v, off, 64);
  return v;
}

__device__ __forceinline__ float block_reduce_256(float v) {
  __shared__ float sm[4];
  v = wave_reduce(v);
  if ((threadIdx.x & 63) == 0) sm[threadIdx.x >> 6] = v;
  __syncthreads();
  return (threadIdx.x == 0) ? (sm[0] + sm[1] + sm[2] + sm[3]) : 0.0f;
}

// ---------------- lam: inv(0.5*(||X2 row||^2 + eps)) ----------------
__global__ __launch_bounds__(256) void lam_kernel(const float* __restrict__ X,
                                                  float* __restrict__ invlam) {
  int row = blockIdx.x;
  const float* xr = X + (size_t)(NQ2 + row) * NT;
  float s = 0.f;
  for (int k = threadIdx.x * 4; k < NT; k += 1024) {
    float4 v = *(const float4*)(xr + k);
    s += v.x * v.x + v.y * v.y + v.z * v.z + v.w * v.w;
  }
  float tot = block_reduce_256(s);
  if (threadIdx.x == 0) invlam[row] = 1.0f / (0.5f * (tot + FEPS));
}

// ---------------- split-K transposed GEMV: part[ch][col] = sum_i A[i][col] v[i] ----
__global__ __launch_bounds__(256) void tgemv_part_kernel(const float* __restrict__ A,
                                                         const float* __restrict__ v,
                                                         float* __restrict__ part) {
  int col = blockIdx.x * 256 + threadIdx.x;
  int ch = blockIdx.y;
  int i0 = ch * (NQ2 / GCH), i1 = i0 + NQ2 / GCH;
  float s = 0.f;
#pragma unroll 4
  for (int i = i0; i < i1; i++) s = fmaf(A[(size_t)i * NQ2 + col], v[i], s);
  part[(size_t)ch * NQ2 + col] = s;
}

// FM 0: c = sum*invlam + D12 u   FM 1: r += 0.5*sum   FM 2: dst = sum
template <int FM>
__global__ __launch_bounds__(256) void finish_kernel(const float* __restrict__ part,
                                                     const float* __restrict__ invlam,
                                                     const float* __restrict__ D12,
                                                     const float* __restrict__ u,
                                                     float* __restrict__ dst) {
  int col = blockIdx.x * 256 + threadIdx.x;
  float s = 0.f;
#pragma unroll
  for (int ch = 0; ch < GCH; ch++) s += part[(size_t)ch * NQ2 + col];
  if (FM == 0) {
    float d = 0.f;
#pragma unroll
    for (int j = 0; j < NUU; j++) d += D12[(size_t)col * NUU + j] * u[j];
    dst[col] = s * invlam[col] + d;
  } else if (FM == 1) {
    dst[col] += 0.5f * s;
  } else {
    dst[col] = s;
  }
}

// ============ MFMA SYRK (bf16 hi/lo split): C = A A^T (+eps diag), lower 128-tiles ====
__global__ __launch_bounds__(256) void syrk_mfma_kernel(const float* __restrict__ A,
                                                        int lda, int K,
                                                        float* __restrict__ C, float eps) {
  int L = blockIdx.x;
  int bi = (int)((sqrtf(8.0f * (float)L + 1.0f) - 1.0f) * 0.5f);
  while ((bi + 1) * (bi + 2) / 2 <= L) bi++;
  while (bi * (bi + 1) / 2 > L) bi--;
  int bj = L - bi * (bi + 1) / 2;
  int row0 = bi * 128, col0 = bj * 128;

  // fragment-major LDS: granule g in [0,512): row=(g>>6)*16+(g&15), k=((g>>4)&3)*8..+8
  __shared__ __align__(16) short Ah[4096], Al[4096], Bh[4096], Bl[4096];

  int tid = threadIdx.x;
  int l = tid & 63;
  int w = tid >> 6;
  int wr = w >> 1, wc = w & 1;

  // staging granules: tid and tid+256 for both A-panel and B-panel
  int g0 = tid, g1 = tid + 256;
  int ar0 = (g0 >> 6) * 16 + (g0 & 15), ak0 = ((g0 >> 4) & 3) * 8;
  int ar1 = (g1 >> 6) * 16 + (g1 & 15), ak1 = ((g1 >> 4) & 3) * 8;

  const float* pa0 = A + (size_t)(row0 + ar0) * lda + ak0;
  const float* pa1 = A + (size_t)(row0 + ar1) * lda + ak1;
  const float* pb0 = A + (size_t)(col0 + ar0) * lda + ak0;
  const float* pb1 = A + (size_t)(col0 + ar1) * lda + ak1;

  floatx4 acc[4][4];
#pragma unroll
  for (int m = 0; m < 4; m++)
#pragma unroll
    for (int n = 0; n < 4; n++) acc[m][n] = (floatx4){0.f, 0.f, 0.f, 0.f};

  float xa0[8], xa1[8], xb0[8], xb1[8];
  {
    float4 t0 = *(const float4*)(pa0), t1 = *(const float4*)(pa0 + 4);
    xa0[0]=t0.x; xa0[1]=t0.y; xa0[2]=t0.z; xa0[3]=t0.w; xa0[4]=t1.x; xa0[5]=t1.y; xa0[6]=t1.z; xa0[7]=t1.w;
    t0 = *(const float4*)(pa1); t1 = *(const float4*)(pa1 + 4);
    xa1[0]=t0.x; xa1[1]=t0.y; xa1[2]=t0.z; xa1[3]=t0.w; xa1[4]=t1.x; xa1[5]=t1.y; xa1[6]=t1.z; xa1[7]=t1.w;
    t0 = *(const float4*)(pb0); t1 = *(const float4*)(pb0 + 4);
    xb0[0]=t0.x; xb0[1]=t0.y; xb0[2]=t0.z; xb0[3]=t0.w; xb0[4]=t1.x; xb0[5]=t1.y; xb0[6]=t1.z; xb0[7]=t1.w;
    t0 = *(const float4*)(pb1); t1 = *(const float4*)(pb1 + 4);
    xb1[0]=t0.x; xb1[1]=t0.y; xb1[2]=t0.z; xb1[3]=t0.w; xb1[4]=t1.x; xb1[5]=t1.y; xb1[6]=t1.z; xb1[7]=t1.w;
  }

  for (int k0 = 0; k0 < K; k0 += 32) {
    __syncthreads();
    // convert + store staged granules
    {
      short8 h, lo;
#pragma unroll
      for (int j = 0; j < 8; j++) { unsigned short hb = f2bf(xa0[j]); h[j] = (short)hb; lo[j] = (short)f2bf(xa0[j] - bf2f(hb)); }
      *(short8*)&Ah[g0 * 8] = h; *(short8*)&Al[g0 * 8] = lo;
#pragma unroll
      for (int j = 0; j < 8; j++) { unsigned short hb = f2bf(xa1[j]); h[j] = (short)hb; lo[j] = (short)f2bf(xa1[j] - bf2f(hb)); }
      *(short8*)&Ah[g1 * 8] = h; *(short8*)&Al[g1 * 8] = lo;
#pragma unroll
      for (int j = 0; j < 8; j++) { unsigned short hb = f2bf(xb0[j]); h[j] = (short)hb; lo[j] = (short)f2bf(xb0[j] - bf2f(hb)); }
      *(short8*)&Bh[g0 * 8] = h; *(short8*)&Bl[g0 * 8] = lo;
#pragma unroll
      for (int j = 0; j < 8; j++) { unsigned short hb = f2bf(xb1[j]); h[j] = (short)hb; lo[j] = (short)f2bf(xb1[j] - bf2f(hb)); }
      *(short8*)&Bh[g1 * 8] = h; *(short8*)&Bl[g1 * 8] = lo;
    }
    __syncthreads();
    if (k0 + 32 < K) {
      const float* q = pa0 + k0 + 32;
      float4 t0 = *(const float4*)(q), t1 = *(const float4*)(q + 4);
      xa0[0]=t0.x; xa0[1]=t0.y; xa0[2]=t0.z; xa0[3]=t0.w; xa0[4]=t1.x; xa0[5]=t1.y; xa0[6]=t1.z; xa0[7]=t1.w;
      q = pa1 + k0 + 32; t0 = *(const float4*)(q); t1 = *(const float4*)(q + 4);
      xa1[0]=t0.x; xa1[1]=t0.y; xa1[2]=t0.z; xa1[3]=t0.w; xa1[4]=t1.x; xa1[5]=t1.y; xa1[6]=t1.z; xa1[7]=t1.w;
      q = pb0 + k0 + 32; t0 = *(const float4*)(q); t1 = *(const float4*)(q + 4);
      xb0[0]=t0.x; xb0[1]=t0.y; xb0[2]=t0.z; xb0[3]=t0.w; xb0[4]=t1.x; xb0[5]=t1.y; xb0[6]=t1.z; xb0[7]=t1.w;
      q = pb1 + k0 + 32; t0 = *(const float4*)(q); t1 = *(const float4*)(q + 4);
      xb1[0]=t0.x; xb1[1]=t0.y; xb1[2]=t0.z; xb1[3]=t0.w; xb1[4]=t1.x; xb1[5]=t1.y; xb1[6]=t1.z; xb1[7]=t1.w;
    }
    short8 amh[4], aml[4], bnh[4], bnl[4];
#pragma unroll
    for (int m = 0; m < 4; m++) {
      int ga = ((wr * 4 + m) * 64 + l) * 8;
      amh[m] = *(const short8*)&Ah[ga];
      aml[m] = *(const short8*)&Al[ga];
    }
#pragma unroll
    for (int n = 0; n < 4; n++) {
      int gb = ((wc * 4 + n) * 64 + l) * 8;
      bnh[n] = *(const short8*)&Bh[gb];
      bnl[n] = *(const short8*)&Bl[gb];
    }
#pragma unroll
    for (int m = 0; m < 4; m++)
#pragma unroll
      for (int n = 0; n < 4; n++) {
        acc[m][n] = __builtin_amdgcn_mfma_f32_16x16x32_bf16(amh[m], bnh[n], acc[m][n], 0, 0, 0);
        acc[m][n] = __builtin_amdgcn_mfma_f32_16x16x32_bf16(amh[m], bnl[n], acc[m][n], 0, 0, 0);
        acc[m][n] = __builtin_amdgcn_mfma_f32_16x16x32_bf16(aml[m], bnh[n], acc[m][n], 0, 0, 0);
      }
  }

  int lr = (l >> 4) * 4;
  int lc = l & 15;
#pragma unroll
  for (int m = 0; m < 4; m++)
#pragma unroll
    for (int n = 0; n < 4; n++)
#pragma unroll
      for (int r = 0; r < 4; r++) {
        int gi = row0 + wr * 64 + m * 16 + lr + r;
        int gj = col0 + wc * 64 + n * 16 + lc;
        float v = acc[m][n][r];
        if (gi == gj) v += eps;
        C[(size_t)gi * NQ2 + gj] = v;
      }
}

// ============ Cooperative blocked Cholesky (in-place lower, NB=64) ============
__global__ __launch_bounds__(256) void chol_coop_kernel(float* __restrict__ M_) {
  cg::grid_group grid = cg::this_grid();
  __shared__ float L11[NB][NB + 1];
  __shared__ float As[NB][NB + 1];
  __shared__ float Bs[NB][NB + 1];
  int tid = threadIdx.x;
  int wg = blockIdx.x;
  int nwg = gridDim.x;

  for (int k = 0; k < NBLK; k++) {
    int b0 = k * NB;
    // phase 1: diagonal block factor (WG 0)
    if (wg == 0) {
      for (int e = tid; e < NB * NB; e += 256) {
        int rr = e >> 6, cc = e & 63;
        L11[rr][cc] = M_[(size_t)(b0 + rr) * NQ2 + b0 + cc];
      }
      __syncthreads();
      for (int j = 0; j < NB; j++) {
        if (tid == 0) L11[j][j] = sqrtf(fmaxf(L11[j][j], 1e-12f));
        __syncthreads();
        if (tid > j && tid < NB) L11[tid][j] /= L11[j][j];
        __syncthreads();
        for (int e = tid; e < NB * NB; e += 256) {
          int rr = e >> 6, cc = e & 63;
          if (rr > j && cc > j && cc <= rr) L11[rr][cc] -= L11[rr][j] * L11[cc][j];
        }
        __syncthreads();
      }
      for (int e = tid; e < NB * NB; e += 256) {
        int rr = e >> 6, cc = e & 63;
        if (cc <= rr) M_[(size_t)(b0 + rr) * NQ2 + b0 + cc] = L11[rr][cc];
      }
    }
    grid.sync();

    int rows_below = NQ2 - b0 - NB;
    // phase 2: panel solve L21 = A21 L11^{-T}  (all WGs)
    if (rows_below > 0) {
      for (int e = tid; e < NB * NB; e += 256) {
        int rr = e >> 6, cc = e & 63;
        L11[rr][cc] = M_[(size_t)(b0 + rr) * NQ2 + b0 + cc];
      }
      __syncthreads();
      int row = b0 + NB + wg * 256 + tid;
      if (row < NQ2) {
        float v[NB];
        const float* ar = M_ + (size_t)row * NQ2 + b0;
#pragma unroll
        for (int j = 0; j < NB; j += 4) {
          float4 a = *(const float4*)(ar + j);
          v[j] = a.x; v[j + 1] = a.y; v[j + 2] = a.z; v[j + 3] = a.w;
        }
#pragma unroll
        for (int j = 0; j < NB; j++) {
          float s = v[j];
#pragma unroll
          for (int tt = 0; tt < j; tt++) s -= v[tt] * L11[j][tt];
          v[j] = s / L11[j][j];
        }
        float* wrp = M_ + (size_t)row * NQ2 + b0;
#pragma unroll
        for (int j = 0; j < NB; j += 4) {
          float4 a; a.x = v[j]; a.y = v[j + 1]; a.z = v[j + 2]; a.w = v[j + 3];
          *(float4*)(wrp + j) = a;
        }
      }
      __syncthreads();
    }
    grid.sync();

    // phase 3: trailing update A22 -= L21 L21^T (lower tiles), tiles spread over WGs
    int m = NBLK - 1 - k;
    int ntiles = m * (m + 1) / 2;
    for (int T = wg; T < ntiles; T += nwg) {
      int bi_ = (int)((sqrtf(8.0f * (float)T + 1.0f) - 1.0f) * 0.5f);
      while ((bi_ + 1) * (bi_ + 2) / 2 <= T) bi_++;
      while (bi_ * (bi_ + 1) / 2 > T) bi_--;
      int bj_ = T - bi_ * (bi_ + 1) / 2;
      int rr0 = (k + 1 + bi_) * NB, cc0 = (k + 1 + bj_) * NB, kc = b0;
      __syncthreads();
      for (int e = tid; e < NB * NB; e += 256) {
        int rr = e >> 6, cc = e & 63;
        As[rr][cc] = M_[(size_t)(rr0 + rr) * NQ2 + kc + cc];
        Bs[rr][cc] = M_[(size_t)(cc0 + rr) * NQ2 + kc + cc];
      }
      __syncthreads();
      int tx = tid & 15, ty = tid >> 4;
      float acc[4][4] = {{0.f}};
#pragma unroll 8
      for (int t = 0; t < NB; t++) {
        float aa[4], bb[4];
#pragma unroll
        for (int i = 0; i < 4; i++) aa[i] = As[ty * 4 + i][t];
#pragma unroll
        for (int j = 0; j < 4; j++) bb[j] = Bs[tx * 4 + j][t];
#pragma unroll
        for (int i = 0; i < 4; i++)
#pragma unroll
          for (int j = 0; j < 4; j++) acc[i][j] = fmaf(aa[i], bb[j], acc[i][j]);
      }
#pragma unroll
      for (int i = 0; i < 4; i++) {
        float* cp = &M_[(size_t)(rr0 + ty * 4 + i) * NQ2 + cc0 + tx * 4];
        float4 v = *(const float4*)cp;
        v.x -= acc[i][0]; v.y -= acc[i][1]; v.z -= acc[i][2]; v.w -= acc[i][3];
        *(float4*)cp = v;
      }
    }
    grid.sync();
  }
}

// ---------------- blocked forward substitution (readlane serial chain) ----------------
template <int MODE>
__global__ __launch_bounds__(1024) void fwd_solve_kernel(const float* __restrict__ M_,
                                                         const float* __restrict__ rhs,
                                                         const float* __restrict__ invlam,
                                                         float* __restrict__ out) {
  __shared__ float partial[NQ2];
  __shared__ float il[NQ2];
  __shared__ float tile[NB][NB + 1];
  __shared__ float vblk[NB];
  int tid = threadIdx.x;
  int rquad = tid >> 2;
  int l4 = tid & 3;
  for (int i = tid; i < NQ2; i += 1024) {
    partial[i] = rhs[i];
    if (MODE == 0) il[i] = invlam[i];
  }
  __syncthreads();
  for (int b = 0; b < NBLK; b++) {
    int b0 = b * NB;
    for (int e = tid; e < NB * NB; e += 1024) {
      int rr = e >> 6, cc = e & 63;
      tile[rr][cc] = M_[(size_t)(b0 + rr) * NQ2 + b0 + cc];
    }
    __syncthreads();
    if (tid < 64) {
      int l = tid;
      float creg = partial[b0 + l];
      float ilreg = (MODE == 0) ? il[b0 + l] : 0.f;
      float dinv = (MODE == 1) ? (1.0f / tile[l][l]) : 0.f;
      float acc = 0.f;
      float wfin = 0.f;
#pragma unroll
      for (int i = 0; i < NB; i++) {
        float cand;
        if (MODE == 0) cand = fmaxf(creg - acc * ilreg, 0.f);
        else           cand = (creg - acc) * dinv;
        float wi = readlane_f(cand, i);
        acc = fmaf(tile[l][i], wi, acc);
        if (l == i) wfin = wi;
      }
      vblk[l] = wfin;
      out[b0 + l] = wfin;
    }
    __syncthreads();
    for (int base = b0 + NB; base < NQ2; base += 256) {
      int row = base + rquad;
      float acc = 0.f;
      if (row < NQ2) {
        const float* mr = M_ + (size_t)row * NQ2 + b0 + l4 * 16;
        float4 m0 = *(const float4*)(mr);
        float4 m1 = *(const float4*)(mr + 4);
        float4 m2 = *(const float4*)(mr + 8);
        float4 m3 = *(const float4*)(mr + 12);
        const float* vp = &vblk[l4 * 16];
        float4 v0 = *(const float4*)(vp);
        float4 v1 = *(const float4*)(vp + 4);
        float4 v2 = *(const float4*)(vp + 8);
        float4 v3 = *(const float4*)(vp + 12);
        acc = m0.x * v0.x + m0.y * v0.y + m0.z * v0.z + m0.w * v0.w
            + m1.x * v1.x + m1.y * v1.y + m1.z * v1.z + m1.w * v1.w
            + m2.x * v2.x + m2.y * v2.y + m2.z * v2.z + m2.w * v2.w
            + m3.x * v3.x + m3.y * v3.y + m3.z * v3.z + m3.w * v3.w;
      }
      acc += __shfl_xor(acc, 1);
      acc += __shfl_xor(acc, 2);
      if (l4 == 0 && row < NQ2) {
        if (MODE == 0) partial[row] -= acc * il[row];
        else           partial[row] -= acc;
      }
    }
    __syncthreads();
  }
}

// ---------------- blocked backward substitution: L^T z = y ----------------
__global__ __launch_bounds__(1024) void bwd_solve_kernel(const float* __restrict__ M_,
                                                         const float* __restrict__ rhs,
                                                         float* __restrict__ out) {
  __shared__ float partial[NQ2];
  __shared__ float tile[NB][NB + 1];
  __shared__ float vblk[NB];
  int tid = threadIdx.x;
  for (int i = tid; i < NQ2; i += 1024) partial[i] = rhs[i];
  __syncthreads();
  for (int b = NBLK - 1; b >= 0; b--) {
    int b0 = b * NB;
    for (int e = tid; e < NB * NB; e += 1024) {
      int rr = e >> 6, cc = e & 63;
      tile[cc][rr] = M_[(size_t)(b0 + rr) * NQ2 + b0 + cc];
    }
    __syncthreads();
    if (tid < 64) {
      int l = tid;
      float creg = partial[b0 + l];
      float dinv = 1.0f / tile[l][l];
      float acc = 0.f;
      float zfin = 0.f;
#pragma unroll
      for (int i = NB - 1; i >= 0; i--) {
        float cand = (creg - acc) * dinv;
        float zi = readlane_f(cand, i);
        acc = fmaf(tile[l][i], zi, acc);
        if (l == i) zfin = zi;
      }
      vblk[l] = zfin;
      out[b0 + l] = zfin;
    }
    __syncthreads();
    for (int i = tid; i < b0; i += 1024) {
      float acc = 0.f;
#pragma unroll 8
      for (int l = 0; l < NB; l++) acc += M_[(size_t)(b0 + l) * NQ2 + i] * vblk[l];
      partial[i] -= acc;
    }
    __syncthreads();
  }
}

// ---------------- t = -0.5 X1^T x - X2^T w (split over row chunks) ----------------
#define TCH 32
__global__ __launch_bounds__(256) void t_partial_kernel(const float* __restrict__ X,
                                                        const float* __restrict__ x,
                                                        const float* __restrict__ w,
                                                        float* __restrict__ tpart) {
  int k4 = (blockIdx.x * 256 + threadIdx.x) * 4;
  int chunk = blockIdx.y;
  int i0 = chunk * (NT / TCH);
  float4 acc = {0.f, 0.f, 0.f, 0.f};
  for (int i = i0; i < i0 + NT / TCH; i++) {
    float cf = (i < NQ2) ? (-0.5f * x[i]) : (-w[i - NQ2]);
    float4 xv = *(const float4*)(X + (size_t)i * NT + k4);
    acc.x += cf * xv.x; acc.y += cf * xv.y; acc.z += cf * xv.z; acc.w += cf * xv.w;
  }
  *(float4*)(tpart + (size_t)chunk * NT + k4) = acc;
}

__global__ __launch_bounds__(256) void t_reduce_kernel(const float* __restrict__ tpart,
                                                       float* __restrict__ t) {
  int k = blockIdx.x * 256 + threadIdx.x;
  float s = 0.f;
#pragma unroll 8
  for (int ch = 0; ch < TCH; ch++) s += tpart[(size_t)ch * NT + k];
  t[k] = s;
}

// -------- r = X1 t - 0.5 Y1 x - U w - 0.5 eps x  (per-row dot reductions) --------
__global__ __launch_bounds__(256) void r_kernel(const float* __restrict__ X,
                                                const float* __restrict__ Y1,
                                                const float* __restrict__ U,
                                                const float* __restrict__ t,
                                                const float* __restrict__ x,
                                                const float* __restrict__ w,
                                                float* __restrict__ r) {
  int row = blockIdx.x;
  float s1 = 0.f, s2 = 0.f, s3 = 0.f;
  const float* xr = X + (size_t)row * NT;
  for (int k = threadIdx.x * 4; k < NT; k += 1024) {
    float4 a = *(const float4*)(xr + k);
    float4 b = *(const float4*)(t + k);
    s1 += a.x * b.x + a.y * b.y + a.z * b.z + a.w * b.w;
  }
  const float* yr = Y1 + (size_t)row * NQ2;
  const float* ur = U + (size_t)row * NQ2;
  for (int k = threadIdx.x * 4; k < NQ2; k += 1024) {
    float4 a = *(const float4*)(yr + k);
    float4 b = *(const float4*)(x + k);
    s2 += a.x * b.x + a.y * b.y + a.z * b.z + a.w * b.w;
    float4 c2 = *(const float4*)(ur + k);
    float4 d2 = *(const float4*)(w + k);
    s3 += c2.x * d2.x + c2.y * d2.y + c2.z * d2.z + c2.w * d2.w;
  }
  float v = s1 - 0.5f * s2 - s3;
  float tot = block_reduce_256(v);
  if (threadIdx.x == 0) r[row] = tot - 0.5f * FEPS * x[row];
}

// ---------------- IR: res = r - (XP pz1 + eps z) ----------------
__global__ __launch_bounds__(256) void pz2_res_kernel(const float* __restrict__ XP,
                                                      const float* __restrict__ pz1,
                                                      const float* __restrict__ z,
                                                      const float* __restrict__ r,
                                                      float* __restrict__ res) {
  int row = blockIdx.x;
  float s = 0.f;
  const float* xr = XP + (size_t)row * NQ2;
  for (int k = threadIdx.x * 4; k < NQ2; k += 1024) {
    float4 a = *(const float4*)(xr + k);
    float4 b = *(const float4*)(pz1 + k);
    s += a.x * b.x + a.y * b.y + a.z * b.z + a.w * b.w;
  }
  float tot = block_reduce_256(s);
  if (threadIdx.x == 0) res[row] = r[row] - (tot + FEPS * z[row]);
}

__global__ __launch_bounds__(256) void axpy_kernel(float* __restrict__ z,
                                                   const float* __restrict__ dz) {
  int i = blockIdx.x * 256 + threadIdx.x;
  z[i] += dz[i];
}

// ---------------- out = z + B2 u ----------------
__global__ __launch_bounds__(256) void out_kernel(const float* __restrict__ z,
                                                  const float* __restrict__ B2,
                                                  const float* __restrict__ u,
                                                  float* __restrict__ out) {
  int i = blockIdx.x * 256 + threadIdx.x;
  float s = 0.f;
#pragma unroll
  for (int j = 0; j < NUU; j++) s += B2[(size_t)i * NUU + j] * u[j];
  out[i] = z[i] + s;
}

extern "C" void kernel_launch(void* const* d_in, const int* in_sizes, int n_in,
                              void* d_out, int out_size, void* d_ws, size_t ws_size,
                              hipStream_t stream) {
  (void)in_sizes; (void)n_in; (void)out_size; (void)ws_size;
  const float* x   = (const float*)d_in[1];
  const float* u   = (const float*)d_in[2];
  const float* X   = (const float*)d_in[3];
  const float* U   = (const float*)d_in[4];
  const float* Y1  = (const float*)d_in[5];
  const float* XP  = (const float*)d_in[6];
  const float* B2  = (const float*)d_in[7];
  const float* D12 = (const float*)d_in[8];
  float* out = (float*)d_out;

  float* ws     = (float*)d_ws;
  float* M      = ws;                           // 2048*2048, holds H22 then P/L
  float* vecs   = ws + (size_t)NQ2 * NQ2;
  float* invlam = vecs;
  float* c      = vecs + 2048;
  float* w      = vecs + 4096;
  float* r      = vecs + 6144;
  float* y      = vecs + 8192;
  float* z      = vecs + 10240;
  float* dz     = vecs + 12288;
  float* res    = vecs + 14336;
  float* t      = vecs + 16384;                 // 4096 (also reused as pz1)
  float* tpart  = vecs + 20480;                 // 32*4096 (also gpart 16*2048)
  float* gpart  = tpart;

  int nsyrk = (NQ2 / 128) * (NQ2 / 128 + 1) / 2;  // 136
  dim3 gdim(NQ2 / 256, GCH);

  // lam, c = (U^T x)/lam + D12 u
  lam_kernel<<<NQ2, 256, 0, stream>>>(X, invlam);
  tgemv_part_kernel<<<gdim, 256, 0, stream>>>(U, x, gpart);
  finish_kernel<0><<<NQ2 / 256, 256, 0, stream>>>(gpart, invlam, D12, u, c);

  // H22 into M (MFMA bf16-split), then sequential relu-triangular solve for w
  syrk_mfma_kernel<<<nsyrk, 256, 0, stream>>>(X + (size_t)NQ2 * NT, NT, NT, M, 0.0f);
  fwd_solve_kernel<0><<<1, 1024, 0, stream>>>(M, c, invlam, w);

  // r = -0.5 X1 X1^T x - X1 X2^T w - 0.5 Y1 x + 0.5 Y1^T x - U w - 0.5 eps x
  dim3 tg(4, TCH);
  t_partial_kernel<<<tg, 256, 0, stream>>>(X, x, w, tpart);
  t_reduce_kernel<<<NT / 256, 256, 0, stream>>>(tpart, t);
  r_kernel<<<NQ2, 256, 0, stream>>>(X, Y1, U, t, x, w, r);
  tgemv_part_kernel<<<gdim, 256, 0, stream>>>(Y1, x, gpart);
  finish_kernel<1><<<NQ2 / 256, 256, 0, stream>>>(gpart, invlam, D12, u, r);

  // P = XP XP^T + eps I into M (MFMA), then one cooperative Cholesky
  syrk_mfma_kernel<<<nsyrk, 256, 0, stream>>>(XP, NQ2, NQ2, M, FEPS);
  {
    float* Mf = M;
    void* cargs[] = { (void*)&Mf };
    hipLaunchCooperativeKernel((const void*)chol_coop_kernel, dim3(256), dim3(256),
                               cargs, 0, stream);
  }

  // solve P z = r
  fwd_solve_kernel<1><<<1, 1024, 0, stream>>>(M, r, invlam, y);
  bwd_solve_kernel<<<1, 1024, 0, stream>>>(M, y, z);

  // 2 steps of iterative refinement (residual via matvecs, P never re-formed)
  for (int it = 0; it < 2; it++) {
    tgemv_part_kernel<<<gdim, 256, 0, stream>>>(XP, z, gpart);
    finish_kernel<2><<<NQ2 / 256, 256, 0, stream>>>(gpart, invlam, D12, u, t);
    pz2_res_kernel<<<NQ2, 256, 0, stream>>>(XP, t, z, r, res);
    fwd_solve_kernel<1><<<1, 1024, 0, stream>>>(M, res, invlam, y);
    bwd_solve_kernel<<<1, 1024, 0, stream>>>(M, y, dz);
    axpy_kernel<<<NQ2 / 256, 256, 0, stream>>>(z, dz);
  }

  out_kernel<<<NQ2 / 256, 256, 0, stream>>>(z, B2, u, out);
}

// Round 5
// 6229.666 us; speedup vs baseline: 1.2632x; 1.2632x over previous
//
#include <hip/hip_runtime.h>
#include <math.h>

#define NQ2 2048      // nx = nq = 2048
#define NT  4096      // nx + nq
#define NUU 16
#define FEPS 0.01f
#define NB  64
#define NBLK 32       // 2048 / 64
#define GCH 16        // split-K chunks for transposed GEMVs

typedef __attribute__((ext_vector_type(8))) short short8;
typedef __attribute__((ext_vector_type(4))) float floatx4;

__device__ __forceinline__ float readlane_f(float v, int lane) {
  return __int_as_float(__builtin_amdgcn_readlane(__float_as_int(v), lane));
}

__device__ __forceinline__ unsigned short f2bf(float x) {
  unsigned u = __float_as_uint(x);
  unsigned r = u + 0x7FFFu + ((u >> 16) & 1u);
  return (unsigned short)(r >> 16);
}
__device__ __forceinline__ float bf2f(unsigned short h) {
  return __uint_as_float(((unsigned)h) << 16);
}

// ---------------- reductions ----------------
__device__ __forceinline__ float wave_reduce(float v) {
#pragma unroll
  for (int off = 32; off > 0; off >>= 1) v += __shfl_down(v, off, 64);
  return v;
}

__device__ __forceinline__ float block_reduce_256(float v) {
  __shared__ float sm[4];
  v = wave_reduce(v);
  if ((threadIdx.x & 63) == 0) sm[threadIdx.x >> 6] = v;
  __syncthreads();
  return (threadIdx.x == 0) ? (sm[0] + sm[1] + sm[2] + sm[3]) : 0.0f;
}

// ---------------- lam: inv(0.5*(||X2 row||^2 + eps)) ----------------
__global__ __launch_bounds__(256) void lam_kernel(const float* __restrict__ X,
                                                  float* __restrict__ invlam) {
  int row = blockIdx.x;
  const float* xr = X + (size_t)(NQ2 + row) * NT;
  float s = 0.f;
  for (int k = threadIdx.x * 4; k < NT; k += 1024) {
    float4 v = *(const float4*)(xr + k);
    s += v.x * v.x + v.y * v.y + v.z * v.z + v.w * v.w;
  }
  float tot = block_reduce_256(s);
  if (threadIdx.x == 0) invlam[row] = 1.0f / (0.5f * (tot + FEPS));
}

// ---------------- split-K transposed GEMV: part[ch][col] = sum_i A[i][col] v[i] ----
__global__ __launch_bounds__(256) void tgemv_part_kernel(const float* __restrict__ A,
                                                         const float* __restrict__ v,
                                                         float* __restrict__ part) {
  int col = blockIdx.x * 256 + threadIdx.x;
  int ch = blockIdx.y;
  int i0 = ch * (NQ2 / GCH), i1 = i0 + NQ2 / GCH;
  float s = 0.f;
#pragma unroll 4
  for (int i = i0; i < i1; i++) s = fmaf(A[(size_t)i * NQ2 + col], v[i], s);
  part[(size_t)ch * NQ2 + col] = s;
}

// FM 0: c = sum*invlam + D12 u   FM 1: r += 0.5*sum   FM 2: dst = sum
template <int FM>
__global__ __launch_bounds__(256) void finish_kernel(const float* __restrict__ part,
                                                     const float* __restrict__ invlam,
                                                     const float* __restrict__ D12,
                                                     const float* __restrict__ u,
                                                     float* __restrict__ dst) {
  int col = blockIdx.x * 256 + threadIdx.x;
  float s = 0.f;
#pragma unroll
  for (int ch = 0; ch < GCH; ch++) s += part[(size_t)ch * NQ2 + col];
  if (FM == 0) {
    float d = 0.f;
#pragma unroll
    for (int j = 0; j < NUU; j++) d += D12[(size_t)col * NUU + j] * u[j];
    dst[col] = s * invlam[col] + d;
  } else if (FM == 1) {
    dst[col] += 0.5f * s;
  } else {
    dst[col] = s;
  }
}

// ============ MFMA SYRK (bf16 hi/lo split): C = A A^T (+eps diag), lower 128-tiles ====
__global__ __launch_bounds__(256) void syrk_mfma_kernel(const float* __restrict__ A,
                                                        int lda, int K,
                                                        float* __restrict__ C, float eps) {
  int L = blockIdx.x;
  int bi = (int)((sqrtf(8.0f * (float)L + 1.0f) - 1.0f) * 0.5f);
  while ((bi + 1) * (bi + 2) / 2 <= L) bi++;
  while (bi * (bi + 1) / 2 > L) bi--;
  int bj = L - bi * (bi + 1) / 2;
  int row0 = bi * 128, col0 = bj * 128;

  __shared__ __align__(16) short Ah[4096], Al[4096], Bh[4096], Bl[4096];

  int tid = threadIdx.x;
  int l = tid & 63;
  int w = tid >> 6;
  int wr = w >> 1, wc = w & 1;

  int g0 = tid, g1 = tid + 256;
  int ar0 = (g0 >> 6) * 16 + (g0 & 15), ak0 = ((g0 >> 4) & 3) * 8;
  int ar1 = (g1 >> 6) * 16 + (g1 & 15), ak1 = ((g1 >> 4) & 3) * 8;

  const float* pa0 = A + (size_t)(row0 + ar0) * lda + ak0;
  const float* pa1 = A + (size_t)(row0 + ar1) * lda + ak1;
  const float* pb0 = A + (size_t)(col0 + ar0) * lda + ak0;
  const float* pb1 = A + (size_t)(col0 + ar1) * lda + ak1;

  floatx4 acc[4][4];
#pragma unroll
  for (int m = 0; m < 4; m++)
#pragma unroll
    for (int n = 0; n < 4; n++) acc[m][n] = (floatx4){0.f, 0.f, 0.f, 0.f};

  float xa0[8], xa1[8], xb0[8], xb1[8];
  {
    float4 t0 = *(const float4*)(pa0), t1 = *(const float4*)(pa0 + 4);
    xa0[0]=t0.x; xa0[1]=t0.y; xa0[2]=t0.z; xa0[3]=t0.w; xa0[4]=t1.x; xa0[5]=t1.y; xa0[6]=t1.z; xa0[7]=t1.w;
    t0 = *(const float4*)(pa1); t1 = *(const float4*)(pa1 + 4);
    xa1[0]=t0.x; xa1[1]=t0.y; xa1[2]=t0.z; xa1[3]=t0.w; xa1[4]=t1.x; xa1[5]=t1.y; xa1[6]=t1.z; xa1[7]=t1.w;
    t0 = *(const float4*)(pb0); t1 = *(const float4*)(pb0 + 4);
    xb0[0]=t0.x; xb0[1]=t0.y; xb0[2]=t0.z; xb0[3]=t0.w; xb0[4]=t1.x; xb0[5]=t1.y; xb0[6]=t1.z; xb0[7]=t1.w;
    t0 = *(const float4*)(pb1); t1 = *(const float4*)(pb1 + 4);
    xb1[0]=t0.x; xb1[1]=t0.y; xb1[2]=t0.z; xb1[3]=t0.w; xb1[4]=t1.x; xb1[5]=t1.y; xb1[6]=t1.z; xb1[7]=t1.w;
  }

  for (int k0 = 0; k0 < K; k0 += 32) {
    __syncthreads();
    {
      short8 h, lo;
#pragma unroll
      for (int j = 0; j < 8; j++) { unsigned short hb = f2bf(xa0[j]); h[j] = (short)hb; lo[j] = (short)f2bf(xa0[j] - bf2f(hb)); }
      *(short8*)&Ah[g0 * 8] = h; *(short8*)&Al[g0 * 8] = lo;
#pragma unroll
      for (int j = 0; j < 8; j++) { unsigned short hb = f2bf(xa1[j]); h[j] = (short)hb; lo[j] = (short)f2bf(xa1[j] - bf2f(hb)); }
      *(short8*)&Ah[g1 * 8] = h; *(short8*)&Al[g1 * 8] = lo;
#pragma unroll
      for (int j = 0; j < 8; j++) { unsigned short hb = f2bf(xb0[j]); h[j] = (short)hb; lo[j] = (short)f2bf(xb0[j] - bf2f(hb)); }
      *(short8*)&Bh[g0 * 8] = h; *(short8*)&Bl[g0 * 8] = lo;
#pragma unroll
      for (int j = 0; j < 8; j++) { unsigned short hb = f2bf(xb1[j]); h[j] = (short)hb; lo[j] = (short)f2bf(xb1[j] - bf2f(hb)); }
      *(short8*)&Bh[g1 * 8] = h; *(short8*)&Bl[g1 * 8] = lo;
    }
    __syncthreads();
    if (k0 + 32 < K) {
      const float* q = pa0 + k0 + 32;
      float4 t0 = *(const float4*)(q), t1 = *(const float4*)(q + 4);
      xa0[0]=t0.x; xa0[1]=t0.y; xa0[2]=t0.z; xa0[3]=t0.w; xa0[4]=t1.x; xa0[5]=t1.y; xa0[6]=t1.z; xa0[7]=t1.w;
      q = pa1 + k0 + 32; t0 = *(const float4*)(q); t1 = *(const float4*)(q + 4);
      xa1[0]=t0.x; xa1[1]=t0.y; xa1[2]=t0.z; xa1[3]=t0.w; xa1[4]=t1.x; xa1[5]=t1.y; xa1[6]=t1.z; xa1[7]=t1.w;
      q = pb0 + k0 + 32; t0 = *(const float4*)(q); t1 = *(const float4*)(q + 4);
      xb0[0]=t0.x; xb0[1]=t0.y; xb0[2]=t0.z; xb0[3]=t0.w; xb0[4]=t1.x; xb0[5]=t1.y; xb0[6]=t1.z; xb0[7]=t1.w;
      q = pb1 + k0 + 32; t0 = *(const float4*)(q); t1 = *(const float4*)(q + 4);
      xb1[0]=t0.x; xb1[1]=t0.y; xb1[2]=t0.z; xb1[3]=t0.w; xb1[4]=t1.x; xb1[5]=t1.y; xb1[6]=t1.z; xb1[7]=t1.w;
    }
    short8 amh[4], aml[4], bnh[4], bnl[4];
#pragma unroll
    for (int m = 0; m < 4; m++) {
      int ga = ((wr * 4 + m) * 64 + l) * 8;
      amh[m] = *(const short8*)&Ah[ga];
      aml[m] = *(const short8*)&Al[ga];
    }
#pragma unroll
    for (int n = 0; n < 4; n++) {
      int gb = ((wc * 4 + n) * 64 + l) * 8;
      bnh[n] = *(const short8*)&Bh[gb];
      bnl[n] = *(const short8*)&Bl[gb];
    }
#pragma unroll
    for (int m = 0; m < 4; m++)
#pragma unroll
      for (int n = 0; n < 4; n++) {
        acc[m][n] = __builtin_amdgcn_mfma_f32_16x16x32_bf16(amh[m], bnh[n], acc[m][n], 0, 0, 0);
        acc[m][n] = __builtin_amdgcn_mfma_f32_16x16x32_bf16(amh[m], bnl[n], acc[m][n], 0, 0, 0);
        acc[m][n] = __builtin_amdgcn_mfma_f32_16x16x32_bf16(aml[m], bnh[n], acc[m][n], 0, 0, 0);
      }
  }

  int lr = (l >> 4) * 4;
  int lc = l & 15;
#pragma unroll
  for (int m = 0; m < 4; m++)
#pragma unroll
    for (int n = 0; n < 4; n++)
#pragma unroll
      for (int r = 0; r < 4; r++) {
        int gi = row0 + wr * 64 + m * 16 + lr + r;
        int gj = col0 + wc * 64 + n * 16 + lc;
        float v = acc[m][n][r];
        if (gi == gj) v += eps;
        C[(size_t)gi * NQ2 + gj] = v;
      }
}

// ======== Cholesky step: fused diag-factor (redundant per WG) + panel TRSM ========
__global__ __launch_bounds__(256) void chol_panel2_kernel(float* __restrict__ M_, int k) {
  __shared__ float L11[NB][NB + 1];
  int b0 = k * NB;
  int tid = threadIdx.x;
  // load diag block (full tile is valid: SYRK writes full tiles; trail updates full diag tiles)
  for (int e = tid; e < NB * NB; e += 256) {
    int rr = e >> 6, cc = e & 63;
    L11[rr][cc] = M_[(size_t)(b0 + rr) * NQ2 + b0 + cc];
  }
  __syncthreads();
  // in-LDS right-looking Cholesky of the 64x64 block (256 threads)
  for (int j = 0; j < NB; j++) {
    if (tid == 0) L11[j][j] = sqrtf(fmaxf(L11[j][j], 1e-12f));
    __syncthreads();
    if (tid > j && tid < NB) L11[tid][j] /= L11[j][j];
    __syncthreads();
    for (int e = tid; e < NB * NB; e += 256) {
      int rr = e >> 6, cc = e & 63;
      if (rr > j && cc > j && cc <= rr) L11[rr][cc] -= L11[rr][j] * L11[cc][j];
    }
    __syncthreads();
  }
  // WG0 stores factored diag (lower) back
  if (blockIdx.x == 0) {
    for (int e = tid; e < NB * NB; e += 256) {
      int rr = e >> 6, cc = e & 63;
      if (cc <= rr) M_[(size_t)(b0 + rr) * NQ2 + b0 + cc] = L11[rr][cc];
    }
  }
  // panel TRSM: L21 = A21 L11^{-T}
  int row = b0 + NB + blockIdx.x * 256 + tid;
  if (row >= NQ2) return;
  float v[NB];
  const float* ar = M_ + (size_t)row * NQ2 + b0;
#pragma unroll
  for (int j = 0; j < NB; j += 4) {
    float4 a = *(const float4*)(ar + j);
    v[j] = a.x; v[j + 1] = a.y; v[j + 2] = a.z; v[j + 3] = a.w;
  }
#pragma unroll
  for (int j = 0; j < NB; j++) {
    float s = v[j];
#pragma unroll
    for (int tt = 0; tt < j; tt++) s -= v[tt] * L11[j][tt];
    v[j] = s / L11[j][j];
  }
  float* wrp = M_ + (size_t)row * NQ2 + b0;
#pragma unroll
  for (int j = 0; j < NB; j += 4) {
    float4 a; a.x = v[j]; a.y = v[j + 1]; a.z = v[j + 2]; a.w = v[j + 3];
    *(float4*)(wrp + j) = a;
  }
}

// ---------------- Cholesky: trailing update A22 -= L21 L21^T (lower tiles) --------
__global__ __launch_bounds__(256) void chol_trail_kernel(float* __restrict__ M_, int k) {
  int L = blockIdx.x;
  int bi_ = (int)((sqrtf(8.0f * (float)L + 1.0f) - 1.0f) * 0.5f);
  while ((bi_ + 1) * (bi_ + 2) / 2 <= L) bi_++;
  while (bi_ * (bi_ + 1) / 2 > L) bi_--;
  int bj_ = L - bi_ * (bi_ + 1) / 2;
  int bi = k + 1 + bi_, bj = k + 1 + bj_;
  int row0 = bi * NB, col0 = bj * NB, kc = k * NB;
  __shared__ float As[NB][NB + 1];
  __shared__ float Bs[NB][NB + 1];
  int tid = threadIdx.x;
  for (int e = tid; e < NB * NB; e += 256) {
    int rr = e >> 6, cc = e & 63;
    As[rr][cc] = M_[(size_t)(row0 + rr) * NQ2 + kc + cc];
    Bs[rr][cc] = M_[(size_t)(col0 + rr) * NQ2 + kc + cc];
  }
  __syncthreads();
  int tx = tid & 15, ty = tid >> 4;
  float acc[4][4] = {{0.f}};
#pragma unroll 8
  for (int t = 0; t < NB; t++) {
    float aa[4], bb[4];
#pragma unroll
    for (int i = 0; i < 4; i++) aa[i] = As[ty * 4 + i][t];
#pragma unroll
    for (int j = 0; j < 4; j++) bb[j] = Bs[tx * 4 + j][t];
#pragma unroll
    for (int i = 0; i < 4; i++)
#pragma unroll
      for (int j = 0; j < 4; j++) acc[i][j] = fmaf(aa[i], bb[j], acc[i][j]);
  }
#pragma unroll
  for (int i = 0; i < 4; i++) {
    float* cp = &M_[(size_t)(row0 + ty * 4 + i) * NQ2 + col0 + tx * 4];
    float4 v = *(const float4*)cp;
    v.x -= acc[i][0]; v.y -= acc[i][1]; v.z -= acc[i][2]; v.w -= acc[i][3];
    *(float4*)cp = v;
  }
}

// ---------------- blocked forward substitution (readlane serial chain) ----------------
// MODE 0: w_i = relu(c_i - (sum_{j<i} M[i,j] w_j) * invlam_i)
// MODE 1: y_i = (r_i - sum_{j<i} L[i,j] y_j) / L[i,i]
template <int MODE>
__global__ __launch_bounds__(1024) void fwd_solve_kernel(const float* __restrict__ M_,
                                                         const float* __restrict__ rhs,
                                                         const float* __restrict__ invlam,
                                                         float* __restrict__ out) {
  __shared__ float partial[NQ2];
  __shared__ float il[NQ2];
  __shared__ float tile[NB][NB + 1];
  __shared__ float vblk[NB];
  int tid = threadIdx.x;
  int rquad = tid >> 2;
  int l4 = tid & 3;
  for (int i = tid; i < NQ2; i += 1024) {
    partial[i] = rhs[i];
    if (MODE == 0) il[i] = invlam[i];
  }
  __syncthreads();
  for (int b = 0; b < NBLK; b++) {
    int b0 = b * NB;
    for (int e = tid; e < NB * NB; e += 1024) {
      int rr = e >> 6, cc = e & 63;
      tile[rr][cc] = M_[(size_t)(b0 + rr) * NQ2 + b0 + cc];
    }
    __syncthreads();
    if (tid < 64) {
      int l = tid;
      float creg = partial[b0 + l];
      float ilreg = (MODE == 0) ? il[b0 + l] : 0.f;
      float dinv = (MODE == 1) ? (1.0f / tile[l][l]) : 0.f;
      float acc = 0.f;
      float wfin = 0.f;
#pragma unroll
      for (int i = 0; i < NB; i++) {
        float cand;
        if (MODE == 0) cand = fmaxf(creg - acc * ilreg, 0.f);
        else           cand = (creg - acc) * dinv;
        float wi = readlane_f(cand, i);
        acc = fmaf(tile[l][i], wi, acc);
        if (l == i) wfin = wi;
      }
      vblk[l] = wfin;
      out[b0 + l] = wfin;
    }
    __syncthreads();
    // GEMV update: 4 lanes/row, 2 row-blocks unrolled for MLP
    float4 v0 = *(const float4*)(&vblk[l4 * 16]);
    float4 v1 = *(const float4*)(&vblk[l4 * 16 + 4]);
    float4 v2 = *(const float4*)(&vblk[l4 * 16 + 8]);
    float4 v3 = *(const float4*)(&vblk[l4 * 16 + 12]);
    for (int base = b0 + NB; base < NQ2; base += 512) {
      int row0 = base + rquad;
      int row1 = row0 + 256;
      float acc0 = 0.f, acc1 = 0.f;
      if (row0 < NQ2) {
        const float* mr = M_ + (size_t)row0 * NQ2 + b0 + l4 * 16;
        float4 m0 = *(const float4*)(mr);
        float4 m1 = *(const float4*)(mr + 4);
        float4 m2 = *(const float4*)(mr + 8);
        float4 m3 = *(const float4*)(mr + 12);
        acc0 = m0.x * v0.x + m0.y * v0.y + m0.z * v0.z + m0.w * v0.w
             + m1.x * v1.x + m1.y * v1.y + m1.z * v1.z + m1.w * v1.w
             + m2.x * v2.x + m2.y * v2.y + m2.z * v2.z + m2.w * v2.w
             + m3.x * v3.x + m3.y * v3.y + m3.z * v3.z + m3.w * v3.w;
      }
      if (row1 < NQ2) {
        const float* mr = M_ + (size_t)row1 * NQ2 + b0 + l4 * 16;
        float4 m0 = *(const float4*)(mr);
        float4 m1 = *(const float4*)(mr + 4);
        float4 m2 = *(const float4*)(mr + 8);
        float4 m3 = *(const float4*)(mr + 12);
        acc1 = m0.x * v0.x + m0.y * v0.y + m0.z * v0.z + m0.w * v0.w
             + m1.x * v1.x + m1.y * v1.y + m1.z * v1.z + m1.w * v1.w
             + m2.x * v2.x + m2.y * v2.y + m2.z * v2.z + m2.w * v2.w
             + m3.x * v3.x + m3.y * v3.y + m3.z * v3.z + m3.w * v3.w;
      }
      acc0 += __shfl_xor(acc0, 1);
      acc0 += __shfl_xor(acc0, 2);
      acc1 += __shfl_xor(acc1, 1);
      acc1 += __shfl_xor(acc1, 2);
      if (l4 == 0) {
        if (row0 < NQ2) {
          if (MODE == 0) partial[row0] -= acc0 * il[row0];
          else           partial[row0] -= acc0;
        }
        if (row1 < NQ2) {
          if (MODE == 0) partial[row1] -= acc1 * il[row1];
          else           partial[row1] -= acc1;
        }
      }
    }
    __syncthreads();
  }
}

// ---------------- blocked backward substitution: L^T z = y ----------------
__global__ __launch_bounds__(1024) void bwd_solve_kernel(const float* __restrict__ M_,
                                                         const float* __restrict__ rhs,
                                                         float* __restrict__ out) {
  __shared__ float partial[NQ2];
  __shared__ float tile[NB][NB + 1];  // tile[a][b] = L[b0+b][b0+a]
  __shared__ float vblk[NB];
  int tid = threadIdx.x;
  for (int i = tid; i < NQ2; i += 1024) partial[i] = rhs[i];
  __syncthreads();
  for (int b = NBLK - 1; b >= 0; b--) {
    int b0 = b * NB;
    for (int e = tid; e < NB * NB; e += 1024) {
      int rr = e >> 6, cc = e & 63;
      tile[cc][rr] = M_[(size_t)(b0 + rr) * NQ2 + b0 + cc];
    }
    __syncthreads();
    if (tid < 64) {
      int l = tid;
      float creg = partial[b0 + l];
      float dinv = 1.0f / tile[l][l];
      float acc = 0.f;
      float zfin = 0.f;
#pragma unroll
      for (int i = NB - 1; i >= 0; i--) {
        float cand = (creg - acc) * dinv;
        float zi = readlane_f(cand, i);
        acc = fmaf(tile[l][i], zi, acc);
        if (l == i) zfin = zi;
      }
      vblk[l] = zfin;
      out[b0 + l] = zfin;
    }
    __syncthreads();
    for (int i = tid; i < b0; i += 1024) {
      float acc = 0.f;
#pragma unroll 16
      for (int l = 0; l < NB; l++) acc += M_[(size_t)(b0 + l) * NQ2 + i] * vblk[l];
      partial[i] -= acc;
    }
    __syncthreads();
  }
}

// ---------------- t = -0.5 X1^T x - X2^T w (split over row chunks) ----------------
#define TCH 32
__global__ __launch_bounds__(256) void t_partial_kernel(const float* __restrict__ X,
                                                        const float* __restrict__ x,
                                                        const float* __restrict__ w,
                                                        float* __restrict__ tpart) {
  int k4 = (blockIdx.x * 256 + threadIdx.x) * 4;
  int chunk = blockIdx.y;
  int i0 = chunk * (NT / TCH);
  float4 acc = {0.f, 0.f, 0.f, 0.f};
  for (int i = i0; i < i0 + NT / TCH; i++) {
    float cf = (i < NQ2) ? (-0.5f * x[i]) : (-w[i - NQ2]);
    float4 xv = *(const float4*)(X + (size_t)i * NT + k4);
    acc.x += cf * xv.x; acc.y += cf * xv.y; acc.z += cf * xv.z; acc.w += cf * xv.w;
  }
  *(float4*)(tpart + (size_t)chunk * NT + k4) = acc;
}

__global__ __launch_bounds__(256) void t_reduce_kernel(const float* __restrict__ tpart,
                                                       float* __restrict__ t) {
  int k = blockIdx.x * 256 + threadIdx.x;
  float s = 0.f;
#pragma unroll 8
  for (int ch = 0; ch < TCH; ch++) s += tpart[(size_t)ch * NT + k];
  t[k] = s;
}

// -------- r = X1 t - 0.5 Y1 x - U w - 0.5 eps x  (per-row dot reductions) --------
__global__ __launch_bounds__(256) void r_kernel(const float* __restrict__ X,
                                                const float* __restrict__ Y1,
                                                const float* __restrict__ U,
                                                const float* __restrict__ t,
                                                const float* __restrict__ x,
                                                const float* __restrict__ w,
                                                float* __restrict__ r) {
  int row = blockIdx.x;
  float s1 = 0.f, s2 = 0.f, s3 = 0.f;
  const float* xr = X + (size_t)row * NT;
  for (int k = threadIdx.x * 4; k < NT; k += 1024) {
    float4 a = *(const float4*)(xr + k);
    float4 b = *(const float4*)(t + k);
    s1 += a.x * b.x + a.y * b.y + a.z * b.z + a.w * b.w;
  }
  const float* yr = Y1 + (size_t)row * NQ2;
  const float* ur = U + (size_t)row * NQ2;
  for (int k = threadIdx.x * 4; k < NQ2; k += 1024) {
    float4 a = *(const float4*)(yr + k);
    float4 b = *(const float4*)(x + k);
    s2 += a.x * b.x + a.y * b.y + a.z * b.z + a.w * b.w;
    float4 c2 = *(const float4*)(ur + k);
    float4 d2 = *(const float4*)(w + k);
    s3 += c2.x * d2.x + c2.y * d2.y + c2.z * d2.z + c2.w * d2.w;
  }
  float v = s1 - 0.5f * s2 - s3;
  float tot = block_reduce_256(v);
  if (threadIdx.x == 0) r[row] = tot - 0.5f * FEPS * x[row];
}

// ---------------- IR: res = r - (XP pz1 + eps z) ----------------
__global__ __launch_bounds__(256) void pz2_res_kernel(const float* __restrict__ XP,
                                                      const float* __restrict__ pz1,
                                                      const float* __restrict__ z,
                                                      const float* __restrict__ r,
                                                      float* __restrict__ res) {
  int row = blockIdx.x;
  float s = 0.f;
  const float* xr = XP + (size_t)row * NQ2;
  for (int k = threadIdx.x * 4; k < NQ2; k += 1024) {
    float4 a = *(const float4*)(xr + k);
    float4 b = *(const float4*)(pz1 + k);
    s += a.x * b.x + a.y * b.y + a.z * b.z + a.w * b.w;
  }
  float tot = block_reduce_256(s);
  if (threadIdx.x == 0) res[row] = r[row] - (tot + FEPS * z[row]);
}

__global__ __launch_bounds__(256) void axpy_kernel(float* __restrict__ z,
                                                   const float* __restrict__ dz) {
  int i = blockIdx.x * 256 + threadIdx.x;
  z[i] += dz[i];
}

// ---------------- out = z + B2 u ----------------
__global__ __launch_bounds__(256) void out_kernel(const float* __restrict__ z,
                                                  const float* __restrict__ B2,
                                                  const float* __restrict__ u,
                                                  float* __restrict__ out) {
  int i = blockIdx.x * 256 + threadIdx.x;
  float s = 0.f;
#pragma unroll
  for (int j = 0; j < NUU; j++) s += B2[(size_t)i * NUU + j] * u[j];
  out[i] = z[i] + s;
}

extern "C" void kernel_launch(void* const* d_in, const int* in_sizes, int n_in,
                              void* d_out, int out_size, void* d_ws, size_t ws_size,
                              hipStream_t stream) {
  (void)in_sizes; (void)n_in; (void)out_size; (void)ws_size;
  const float* x   = (const float*)d_in[1];
  const float* u   = (const float*)d_in[2];
  const float* X   = (const float*)d_in[3];
  const float* U   = (const float*)d_in[4];
  const float* Y1  = (const float*)d_in[5];
  const float* XP  = (const float*)d_in[6];
  const float* B2  = (const float*)d_in[7];
  const float* D12 = (const float*)d_in[8];
  float* out = (float*)d_out;

  float* ws     = (float*)d_ws;
  float* M      = ws;                           // 2048*2048, holds H22 then P/L
  float* vecs   = ws + (size_t)NQ2 * NQ2;
  float* invlam = vecs;
  float* c      = vecs + 2048;
  float* w      = vecs + 4096;
  float* r      = vecs + 6144;
  float* y      = vecs + 8192;
  float* z      = vecs + 10240;
  float* dz     = vecs + 12288;
  float* res    = vecs + 14336;
  float* t      = vecs + 16384;                 // 4096 (also reused as pz1)
  float* tpart  = vecs + 20480;                 // 32*4096 (also gpart 16*2048)
  float* gpart  = tpart;

  int nsyrk = (NQ2 / 128) * (NQ2 / 128 + 1) / 2;  // 136
  dim3 gdim(NQ2 / 256, GCH);

  // lam, c = (U^T x)/lam + D12 u
  lam_kernel<<<NQ2, 256, 0, stream>>>(X, invlam);
  tgemv_part_kernel<<<gdim, 256, 0, stream>>>(U, x, gpart);
  finish_kernel<0><<<NQ2 / 256, 256, 0, stream>>>(gpart, invlam, D12, u, c);

  // H22 into M (MFMA bf16-split), then sequential relu-triangular solve for w
  syrk_mfma_kernel<<<nsyrk, 256, 0, stream>>>(X + (size_t)NQ2 * NT, NT, NT, M, 0.0f);
  fwd_solve_kernel<0><<<1, 1024, 0, stream>>>(M, c, invlam, w);

  // r = -0.5 X1 X1^T x - X1 X2^T w - 0.5 Y1 x + 0.5 Y1^T x - U w - 0.5 eps x
  dim3 tg(4, TCH);
  t_partial_kernel<<<tg, 256, 0, stream>>>(X, x, w, tpart);
  t_reduce_kernel<<<NT / 256, 256, 0, stream>>>(tpart, t);
  r_kernel<<<NQ2, 256, 0, stream>>>(X, Y1, U, t, x, w, r);
  tgemv_part_kernel<<<gdim, 256, 0, stream>>>(Y1, x, gpart);
  finish_kernel<1><<<NQ2 / 256, 256, 0, stream>>>(gpart, invlam, D12, u, r);

  // P = XP XP^T + eps I into M (MFMA), Cholesky in place (fused panel + trail)
  syrk_mfma_kernel<<<nsyrk, 256, 0, stream>>>(XP, NQ2, NQ2, M, FEPS);
  for (int k = 0; k < NBLK; k++) {
    int rows_below = NQ2 - (k + 1) * NB;
    int nwg = rows_below > 0 ? (rows_below + 255) / 256 : 1;
    chol_panel2_kernel<<<nwg, 256, 0, stream>>>(M, k);
    if (rows_below > 0) {
      int m = NBLK - 1 - k;
      chol_trail_kernel<<<m * (m + 1) / 2, 256, 0, stream>>>(M, k);
    }
  }

  // solve P z = r
  fwd_solve_kernel<1><<<1, 1024, 0, stream>>>(M, r, invlam, y);
  bwd_solve_kernel<<<1, 1024, 0, stream>>>(M, y, z);

  // 2 steps of iterative refinement (residual via matvecs, P never re-formed)
  for (int it = 0; it < 2; it++) {
    tgemv_part_kernel<<<gdim, 256, 0, stream>>>(XP, z, gpart);
    finish_kernel<2><<<NQ2 / 256, 256, 0, stream>>>(gpart, invlam, D12, u, t);
    pz2_res_kernel<<<NQ2, 256, 0, stream>>>(XP, t, z, r, res);
    fwd_solve_kernel<1><<<1, 1024, 0, stream>>>(M, res, invlam, y);
    bwd_solve_kernel<<<1, 1024, 0, stream>>>(M, y, dz);
    axpy_kernel<<<NQ2 / 256, 256, 0, stream>>>(z, dz);
  }

  out_kernel<<<NQ2 / 256, 256, 0, stream>>>(z, B2, u, out);
}